// Round 9
// baseline (241.956 us; speedup 1.0000x reference)
//
#include <hip/hip_runtime.h>
#include <hip/hip_bf16.h>
#include <hip/hip_cooperative_groups.h>
#include <cstdint>
#include <cstddef>

namespace cg = cooperative_groups;

#define TOK 8192
#define HID 1024
#define NE 8
#define FGRID 512

typedef __bf16 bf16x4 __attribute__((ext_vector_type(4)));
typedef __bf16 bf16x8 __attribute__((ext_vector_type(8)));
typedef float floatx4 __attribute__((ext_vector_type(4)));

static __device__ __forceinline__ __bf16 f2bf(float x) {
    unsigned u = __builtin_bit_cast(unsigned, x);
    u += 0x7fffu + ((u >> 16) & 1u);   // RNE (inputs finite)
    unsigned short hs = (unsigned short)(u >> 16);
    return __builtin_bit_cast(__bf16, hs);
}

// ============================================================================
// FUSED cooperative kernel: prep (cvt_wt + cvt_x + route) -> grid.sync() ->
// persistent grouped GEMM (the R3/R5-verified 64x64 depth-2 counted-vmcnt body).
// WHY: cross-round accounting shows dur - GEMM ~= 100-102us every round; fill is
// 41 and prep roofline is ~16 -> ~20-40us of prep-inefficiency + launch gaps.
// One kernel removes the gaps and spreads prep over all 256 CUs; the GEMM phase
// is byte-identical in schedule to the best-measured variant.
// 512 blocks = 2/CU (LDS 49.7KB, 3/CU capacity -> cooperative co-residency safe).
// ============================================================================
__launch_bounds__(256)
__global__ void fused_moe(const float* __restrict__ X, const float* __restrict__ gate,
                          const float* __restrict__ W,
                          __bf16* __restrict__ Xb, __bf16* __restrict__ Wt,
                          const float* __restrict__ Bias,
                          float* __restrict__ scale, int* __restrict__ counts,
                          int* __restrict__ list, float* __restrict__ out) {
    __shared__ __bf16 As[3][64 * 64];
    __shared__ __bf16 Bs[3][64 * 64];
    __shared__ int   tok[64];
    __shared__ float scl[64];
    __shared__ int hcnt[NE];
    __shared__ int hbase[NE];

    const int bid = blockIdx.x;
    const int tid = threadIdx.x;

    // ---------------- Phase A: prep ----------------
    // cvt_wt: 1024 units (128k x 64n tiles), 2 per block.
    for (int u = bid; u < 1024; u += FGRID) {
        const int e  = u >> 7;
        const int rem = u & 127;
        const int kt = rem >> 4;
        const int nt = rem & 15;
        const int k0 = kt * 128, n0 = nt * 64;
        const int cg_ = tid & 15;           // 4 n-cols
        const int rg = tid >> 4;            // 8 k-rows

        const float* src = W + ((size_t)e * HID + k0 + rg * 8) * HID + n0 + cg_ * 4;
        float rr[8][4];
#pragma unroll
        for (int i = 0; i < 8; i++) {
            float4 x = *(const float4*)(src + (size_t)i * HID);
            rr[i][0] = x.x; rr[i][1] = x.y; rr[i][2] = x.z; rr[i][3] = x.w;
        }
        __bf16* dst = Wt + ((size_t)e * HID + n0 + cg_ * 4) * HID + k0 + rg * 8;
#pragma unroll
        for (int j = 0; j < 4; j++) {
            bf16x8 v;
#pragma unroll
            for (int i = 0; i < 8; i++) v[i] = f2bf(rr[i][j]);
            *(bf16x8*)(dst + (size_t)j * HID) = v;
        }
    }

    // cvt_x: 8M elems, 8/thread/iter, 8 iters over 512x256 threads.
#pragma unroll
    for (int it = 0; it < 8; ++it) {
        size_t idx = (size_t)it * (FGRID * 256) + bid * 256 + tid;
        const float4 a0 = *(const float4*)(X + idx * 8);
        const float4 a1 = *(const float4*)(X + idx * 8 + 4);
        bf16x8 v;
        v[0] = f2bf(a0.x); v[1] = f2bf(a0.y); v[2] = f2bf(a0.z); v[3] = f2bf(a0.w);
        v[4] = f2bf(a1.x); v[5] = f2bf(a1.y); v[6] = f2bf(a1.z); v[7] = f2bf(a1.w);
        *(bf16x8*)(Xb + idx * 8) = v;
    }

    // route: blocks 0..31, one token per thread, LDS histogram.
    if (bid < 32) {
        if (tid < NE) hcnt[tid] = 0;
        __syncthreads();
        int tk = bid * 256 + tid;
        float g[NE];
#pragma unroll
        for (int j = 0; j < NE; j++) g[j] = gate[tk * NE + j];
        float gm = g[0]; int best = 0;
#pragma unroll
        for (int j = 1; j < NE; j++) {
            if (g[j] > gm) { gm = g[j]; best = j; }   // strict >: first-max (argmax)
        }
        float s = 0.f;
#pragma unroll
        for (int j = 0; j < NE; j++) s += __expf(g[j] - gm);
        scale[tk] = 1.0f / s;
        int lpos = atomicAdd(&hcnt[best], 1);
        __syncthreads();
        if (tid < NE) hbase[tid] = atomicAdd(&counts[tid], hcnt[tid]);
        __syncthreads();
        list[best * TOK + hbase[best] + lpos] = tk;
    }

    // ---------------- grid-wide barrier ----------------
    cg::this_grid().sync();

    // ---------------- Phase B: persistent grouped GEMM (R3 schedule) ----------------
    const int lane = tid & 63;
    const int wave = tid >> 6;
    const int ln = lane & 15;
    const int q  = lane >> 4;
    const int wm = (wave >> 1) * 32;
    const int wn = (wave & 1) * 32;
    const int rsw = ln & 7;
    const int srow = lane >> 3;
    const int gchunk = ((lane & 7) ^ srow) * 8;

    for (int w = bid; w < 128 * 16 * 8; w += FGRID) {   // e = w&7 constant per block
        const int e  = w & 7;
        const int nt = (w >> 3) & 15;
        const int mt = w >> 7;

        const int cnt = counts[e];
        if (mt * 64 >= cnt) continue;
        const int mvalid = min(64, cnt - mt * 64);
        const int n0 = nt * 64;

        __syncthreads();   // WAR: previous tile fully done with tok/scl/As/Bs
        if (tid < 64) {
            int g = mt * 64 + tid;
            int tk = (g < cnt) ? list[e * TOK + g] : 0;
            tok[tid] = tk;
            scl[tid] = (g < cnt) ? scale[tk] : 0.f;
        }
        __syncthreads();

        const __bf16* aptr[2];
        const __bf16* bptr[2];
#pragma unroll
        for (int i = 0; i < 2; i++) {
            int r = wave * 16 + i * 8 + srow;
            aptr[i] = Xb + (size_t)tok[r] * HID + gchunk;
            bptr[i] = Wt + ((size_t)e * HID + n0 + r) * HID + gchunk;
        }

        floatx4 acc[2][2];
#pragma unroll
        for (int mi = 0; mi < 2; mi++)
#pragma unroll
            for (int ni = 0; ni < 2; ni++) acc[mi][ni] = (floatx4){0.f, 0.f, 0.f, 0.f};

        auto stage = [&](int b, int k0) {
#pragma unroll
            for (int i = 0; i < 2; i++) {
                __builtin_amdgcn_global_load_lds(
                    (const __attribute__((address_space(1))) void*)(aptr[i] + k0),
                    (__attribute__((address_space(3))) void*)(&As[b][(wave * 16 + i * 8) * 64]),
                    16, 0, 0);
                __builtin_amdgcn_global_load_lds(
                    (const __attribute__((address_space(1))) void*)(bptr[i] + k0),
                    (__attribute__((address_space(3))) void*)(&Bs[b][(wave * 16 + i * 8) * 64]),
                    16, 0, 0);
            }
        };

        auto compute = [&](int b) {
            __builtin_amdgcn_s_setprio(1);
#pragma unroll
            for (int kk = 0; kk < 64; kk += 32) {
                const int cb = (kk >> 3) + q;
                const int pos = (cb ^ rsw) * 8;
                bf16x8 af[2], bfv[2];
#pragma unroll
                for (int mi = 0; mi < 2; mi++)
                    af[mi] = *(const bf16x8*)(&As[b][(wm + mi * 16 + ln) * 64 + pos]);
#pragma unroll
                for (int ni = 0; ni < 2; ni++)
                    bfv[ni] = *(const bf16x8*)(&Bs[b][(wn + ni * 16 + ln) * 64 + pos]);
#pragma unroll
                for (int mi = 0; mi < 2; mi++)
#pragma unroll
                    for (int ni = 0; ni < 2; ni++)
                        acc[mi][ni] = __builtin_amdgcn_mfma_f32_16x16x32_bf16(
                            af[mi], bfv[ni], acc[mi][ni], 0, 0, 0);
            }
            __builtin_amdgcn_s_setprio(0);
        };

        // depth-2 pipeline over 16 K-tiles, 3 LDS buffers, counted vmcnt (R3).
        stage(0, 0);
        stage(1, 64);

#pragma unroll
        for (int t = 0; t < 14; ++t) {
            __builtin_amdgcn_s_barrier();                      // WAR on buf[(t+2)%3]
            stage((t + 2) % 3, (t + 2) * 64);                  // 12 outstanding
            asm volatile("s_waitcnt vmcnt(8)" ::: "memory");   // tile t's 4 loads done
            __builtin_amdgcn_s_barrier();                      // tile t visible
            compute(t % 3);
        }
        asm volatile("s_waitcnt vmcnt(4)" ::: "memory");
        __builtin_amdgcn_s_barrier();
        compute(14 % 3);
        asm volatile("s_waitcnt vmcnt(0)" ::: "memory");
        __builtin_amdgcn_s_barrier();
        compute(15 % 3);

        float bn[2];
#pragma unroll
        for (int ni = 0; ni < 2; ni++) bn[ni] = Bias[e * HID + n0 + wn + ni * 16 + ln];

#pragma unroll
        for (int mi = 0; mi < 2; mi++) {
#pragma unroll
            for (int r = 0; r < 4; r++) {
                int row = wm + mi * 16 + q * 4 + r;
                if (row < mvalid) {
                    int t = tok[row];
                    float sc = scl[row];
                    size_t ob = (size_t)t * HID + n0 + wn + ln;
#pragma unroll
                    for (int ni = 0; ni < 2; ni++)
                        __builtin_nontemporal_store(sc * (acc[mi][ni][r] + bn[ni]),
                                                    &out[ob + ni * 16]);
                }
            }
        }
    }
}

// ============================================================================
// Non-cooperative fallback path (also used if cooperative launch fails):
// exact R5 kernels (best measured two-kernel config, 141.5us).
// ============================================================================
__global__ void prep_kernel(const float* __restrict__ X, const float* __restrict__ gate,
                            const float* __restrict__ W,
                            __bf16* __restrict__ Xb, __bf16* __restrict__ Wt,
                            float* __restrict__ scale, int* __restrict__ counts,
                            int* __restrict__ list) {
    const int b = blockIdx.x;
    const int t = threadIdx.x;

    if (b < 1024) {
        const int e  = b >> 7;
        const int rem = b & 127;
        const int kt = rem >> 4;
        const int nt = rem & 15;
        const int k0 = kt * 128, n0 = nt * 64;
        const int cg_ = t & 15;
        const int rg = t >> 4;

        const float* src = W + ((size_t)e * HID + k0 + rg * 8) * HID + n0 + cg_ * 4;
        float rr[8][4];
#pragma unroll
        for (int i = 0; i < 8; i++) {
            float4 x = *(const float4*)(src + (size_t)i * HID);
            rr[i][0] = x.x; rr[i][1] = x.y; rr[i][2] = x.z; rr[i][3] = x.w;
        }
        __bf16* dst = Wt + ((size_t)e * HID + n0 + cg_ * 4) * HID + k0 + rg * 8;
#pragma unroll
        for (int j = 0; j < 4; j++) {
            bf16x8 v;
#pragma unroll
            for (int i = 0; i < 8; i++) v[i] = f2bf(rr[i][j]);
            *(bf16x8*)(dst + (size_t)j * HID) = v;
        }
    } else {
        const int bb = b - 1024;
        size_t idx = (size_t)bb * 256 + t;
        const float4 a0 = *(const float4*)(X + idx * 8);
        const float4 a1 = *(const float4*)(X + idx * 8 + 4);
        bf16x8 v;
        v[0] = f2bf(a0.x); v[1] = f2bf(a0.y); v[2] = f2bf(a0.z); v[3] = f2bf(a0.w);
        v[4] = f2bf(a1.x); v[5] = f2bf(a1.y); v[6] = f2bf(a1.z); v[7] = f2bf(a1.w);
        *(bf16x8*)(Xb + idx * 8) = v;

        if (bb < 32) {
            __shared__ int hcnt[NE];
            __shared__ int hbase[NE];
            if (t < NE) hcnt[t] = 0;
            __syncthreads();
            int tok = bb * 256 + t;
            float g[NE];
#pragma unroll
            for (int j = 0; j < NE; j++) g[j] = gate[tok * NE + j];
            float gm = g[0]; int best = 0;
#pragma unroll
            for (int j = 1; j < NE; j++) {
                if (g[j] > gm) { gm = g[j]; best = j; }
            }
            float s = 0.f;
#pragma unroll
            for (int j = 0; j < NE; j++) s += __expf(g[j] - gm);
            scale[tok] = 1.0f / s;
            int lpos = atomicAdd(&hcnt[best], 1);
            __syncthreads();
            if (t < NE) hbase[t] = atomicAdd(&counts[t], hcnt[t]);
            __syncthreads();
            list[best * TOK + hbase[best] + lpos] = tok;
        }
    }
}

__launch_bounds__(256)
__global__ void moe_gemm_bf16(const __bf16* __restrict__ Xb, const __bf16* __restrict__ Wt,
                              const float* __restrict__ Bias, const float* __restrict__ scale,
                              const int* __restrict__ counts, const int* __restrict__ list,
                              float* __restrict__ out) {
    const int bid = blockIdx.x;
    const int e  = bid & 7;
    const int nt = (bid >> 3) & 15;
    const int mt = bid >> 7;

    const int cnt = counts[e];
    if (mt * 64 >= cnt) return;
    const int mvalid = min(64, cnt - mt * 64);
    const int n0 = nt * 64;

    __shared__ __bf16 As[3][64 * 64];
    __shared__ __bf16 Bs[3][64 * 64];
    __shared__ int   tok[64];
    __shared__ float scl[64];

    const int tid  = threadIdx.x;
    const int lane = tid & 63;
    const int wave = tid >> 6;

    if (tid < 64) {
        int g = mt * 64 + tid;
        int tk = (g < cnt) ? list[e * TOK + g] : 0;
        tok[tid] = tk;
        scl[tid] = (g < cnt) ? scale[tk] : 0.f;
    }
    __syncthreads();

    const int srow = lane >> 3;
    const int gchunk = ((lane & 7) ^ srow) * 8;
    const __bf16* aptr[2];
    const __bf16* bptr[2];
#pragma unroll
    for (int i = 0; i < 2; i++) {
        int r = wave * 16 + i * 8 + srow;
        aptr[i] = Xb + (size_t)tok[r] * HID + gchunk;
        bptr[i] = Wt + ((size_t)e * HID + n0 + r) * HID + gchunk;
    }

    const int ln = lane & 15;
    const int q  = lane >> 4;
    const int wm = (wave >> 1) * 32;
    const int wn = (wave & 1) * 32;
    const int rsw = ln & 7;

    floatx4 acc[2][2];
#pragma unroll
    for (int mi = 0; mi < 2; mi++)
#pragma unroll
        for (int ni = 0; ni < 2; ni++) acc[mi][ni] = (floatx4){0.f, 0.f, 0.f, 0.f};

    auto stage = [&](int b, int k0) {
#pragma unroll
        for (int i = 0; i < 2; i++) {
            __builtin_amdgcn_global_load_lds(
                (const __attribute__((address_space(1))) void*)(aptr[i] + k0),
                (__attribute__((address_space(3))) void*)(&As[b][(wave * 16 + i * 8) * 64]),
                16, 0, 0);
            __builtin_amdgcn_global_load_lds(
                (const __attribute__((address_space(1))) void*)(bptr[i] + k0),
                (__attribute__((address_space(3))) void*)(&Bs[b][(wave * 16 + i * 8) * 64]),
                16, 0, 0);
        }
    };

    auto compute = [&](int b) {
        __builtin_amdgcn_s_setprio(1);
#pragma unroll
        for (int kk = 0; kk < 64; kk += 32) {
            const int cb = (kk >> 3) + q;
            const int pos = (cb ^ rsw) * 8;
            bf16x8 af[2], bfv[2];
#pragma unroll
            for (int mi = 0; mi < 2; mi++)
                af[mi] = *(const bf16x8*)(&As[b][(wm + mi * 16 + ln) * 64 + pos]);
#pragma unroll
            for (int ni = 0; ni < 2; ni++)
                bfv[ni] = *(const bf16x8*)(&Bs[b][(wn + ni * 16 + ln) * 64 + pos]);
#pragma unroll
            for (int mi = 0; mi < 2; mi++)
#pragma unroll
                for (int ni = 0; ni < 2; ni++)
                    acc[mi][ni] = __builtin_amdgcn_mfma_f32_16x16x32_bf16(
                        af[mi], bfv[ni], acc[mi][ni], 0, 0, 0);
        }
        __builtin_amdgcn_s_setprio(0);
    };

    stage(0, 0);
    stage(1, 64);

#pragma unroll
    for (int t = 0; t < 14; ++t) {
        __builtin_amdgcn_s_barrier();
        stage((t + 2) % 3, (t + 2) * 64);
        asm volatile("s_waitcnt vmcnt(8)" ::: "memory");
        __builtin_amdgcn_s_barrier();
        compute(t % 3);
    }
    asm volatile("s_waitcnt vmcnt(4)" ::: "memory");
    __builtin_amdgcn_s_barrier();
    compute(14 % 3);
    asm volatile("s_waitcnt vmcnt(0)" ::: "memory");
    __builtin_amdgcn_s_barrier();
    compute(15 % 3);

    float bn[2];
#pragma unroll
    for (int ni = 0; ni < 2; ni++) bn[ni] = Bias[e * HID + n0 + wn + ni * 16 + ln];

#pragma unroll
    for (int mi = 0; mi < 2; mi++) {
#pragma unroll
        for (int r = 0; r < 4; r++) {
            int row = wm + mi * 16 + q * 4 + r;
            if (row < mvalid) {
                int t = tok[row];
                float sc = scl[row];
                size_t ob = (size_t)t * HID + n0 + wn + ln;
#pragma unroll
                for (int ni = 0; ni < 2; ni++)
                    __builtin_nontemporal_store(sc * (acc[mi][ni][r] + bn[ni]),
                                                &out[ob + ni * 16]);
            }
        }
    }
}

// ---------------- fallback (ws too small): direct fp32 reads, compile-time j ----------------
__launch_bounds__(256)
__global__ void moe_gemm_fb(const float* __restrict__ X, const float* __restrict__ W,
                            const float* __restrict__ Bias, const float* __restrict__ scale,
                            const int* __restrict__ counts, const int* __restrict__ list,
                            float* __restrict__ out) {
    const int bid = blockIdx.x;
    const int e  = bid >> 9;
    const int nt = (bid >> 6) & 7;
    const int mt = bid & 63;
    const int cnt = counts[e];
    if (mt * 128 >= cnt) return;
    const int mvalid = min(128, cnt - mt * 128);
    const int n0 = nt * 128;

    __shared__ __bf16 As[128 * 64];
    __shared__ __bf16 Bs[128 * 64];
    __shared__ int   tok[128];
    __shared__ float scl[128];

    const int tid = threadIdx.x;
    if (tid < 128) {
        int g = mt * 128 + tid;
        int tk = (g < cnt) ? list[e * TOK + g] : 0;
        tok[tid] = tk;
        scl[tid] = (g < cnt) ? scale[tk] : 0.f;
    }
    __syncthreads();

    const int c4 = tid & 15;
    const float* rp[8];
    bool rv[8];
#pragma unroll
    for (int i = 0; i < 8; i++) {
        int m = (tid >> 4) + 16 * i;
        rv[i] = (m < mvalid);
        rp[i] = X + (size_t)tok[m] * HID;
    }
    const int n4 = tid & 31;
    const int kb = tid >> 5;
    const float* wbase = W + (size_t)e * HID * HID + (size_t)(kb * 8) * HID + n0 + n4 * 4;

    const int lane = tid & 63;
    const int ln = lane & 15;
    const int q  = lane >> 4;
    const int wave = tid >> 6;
    const int wm = (wave >> 1) * 64;
    const int wn = (wave & 1) * 64;

    floatx4 acc[4][4];
#pragma unroll
    for (int mi = 0; mi < 4; mi++)
#pragma unroll
        for (int ni = 0; ni < 4; ni++) acc[mi][ni] = (floatx4){0.f, 0.f, 0.f, 0.f};

    for (int k0 = 0; k0 < HID; k0 += 64) {
#pragma unroll
        for (int i = 0; i < 8; i++) {
            int m = (tid >> 4) + 16 * i;
            float4 v = make_float4(0.f, 0.f, 0.f, 0.f);
            if (rv[i]) v = *(const float4*)(rp[i] + k0 + c4 * 4);
            bf16x4 b4;
            b4[0] = f2bf(v.x); b4[1] = f2bf(v.y); b4[2] = f2bf(v.z); b4[3] = f2bf(v.w);
            int chunk = c4 >> 1;
            int addr = m * 64 + ((chunk ^ (m & 7)) * 8) + (c4 & 1) * 4;
            *(bf16x4*)(&As[addr]) = b4;
        }
        {
            const float* wp = wbase + (size_t)k0 * HID;
            float4 rr[8];
#pragma unroll
            for (int r = 0; r < 8; r++) rr[r] = *(const float4*)(wp + (size_t)r * HID);
#pragma unroll
            for (int j = 0; j < 4; j++) {
                int n = n4 * 4 + j;
                int c = kb ^ (n & 7);
                bf16x8 pk;
                pk[0] = f2bf(j == 0 ? rr[0].x : j == 1 ? rr[0].y : j == 2 ? rr[0].z : rr[0].w);
                pk[1] = f2bf(j == 0 ? rr[1].x : j == 1 ? rr[1].y : j == 2 ? rr[1].z : rr[1].w);
                pk[2] = f2bf(j == 0 ? rr[2].x : j == 1 ? rr[2].y : j == 2 ? rr[2].z : rr[2].w);
                pk[3] = f2bf(j == 0 ? rr[3].x : j == 1 ? rr[3].y : j == 2 ? rr[3].z : rr[3].w);
                pk[4] = f2bf(j == 0 ? rr[4].x : j == 1 ? rr[4].y : j == 2 ? rr[4].z : rr[4].w);
                pk[5] = f2bf(j == 0 ? rr[5].x : j == 1 ? rr[5].y : j == 2 ? rr[5].z : rr[5].w);
                pk[6] = f2bf(j == 0 ? rr[6].x : j == 1 ? rr[6].y : j == 2 ? rr[6].z : rr[6].w);
                pk[7] = f2bf(j == 0 ? rr[7].x : j == 1 ? rr[7].y : j == 2 ? rr[7].z : rr[7].w);
                *(bf16x8*)(&Bs[n * 64 + c * 8]) = pk;
            }
        }
        __syncthreads();
#pragma unroll
        for (int kk = 0; kk < 64; kk += 32) {
            const int cbase = (kk >> 3) + q;
            bf16x8 af[4], bfv[4];
#pragma unroll
            for (int mi = 0; mi < 4; mi++) {
                int row = wm + mi * 16 + ln;
                af[mi] = *(const bf16x8*)(&As[row * 64 + ((cbase ^ (row & 7)) * 8)]);
            }
#pragma unroll
            for (int ni = 0; ni < 4; ni++) {
                int n = wn + ni * 16 + ln;
                bfv[ni] = *(const bf16x8*)(&Bs[n * 64 + ((cbase ^ (n & 7)) * 8)]);
            }
#pragma unroll
            for (int mi = 0; mi < 4; mi++)
#pragma unroll
                for (int ni = 0; ni < 4; ni++)
                    acc[mi][ni] = __builtin_amdgcn_mfma_f32_16x16x32_bf16(
                        af[mi], bfv[ni], acc[mi][ni], 0, 0, 0);
        }
        __syncthreads();
    }

    float bn[4];
#pragma unroll
    for (int ni = 0; ni < 4; ni++) bn[ni] = Bias[e * HID + n0 + wn + ni * 16 + ln];
#pragma unroll
    for (int mi = 0; mi < 4; mi++) {
#pragma unroll
        for (int r = 0; r < 4; r++) {
            int row = wm + mi * 16 + q * 4 + r;
            if (row < mvalid) {
                int t = tok[row];
                float sc = scl[row];
                size_t ob = (size_t)t * HID + n0 + wn + ln;
#pragma unroll
                for (int ni = 0; ni < 4; ni++)
                    out[ob + ni * 16] = sc * (acc[mi][ni][r] + bn[ni]);
            }
        }
    }
}

__global__ void route_fb_kernel(const float* __restrict__ gate, float* __restrict__ scale,
                                int* __restrict__ counts, int* __restrict__ list) {
    int t = blockIdx.x * blockDim.x + threadIdx.x;
    if (t >= TOK) return;
    float g[NE];
#pragma unroll
    for (int j = 0; j < NE; j++) g[j] = gate[t * NE + j];
    float gm = g[0]; int best = 0;
#pragma unroll
    for (int j = 1; j < NE; j++) {
        if (g[j] > gm) { gm = g[j]; best = j; }
    }
    float s = 0.f;
#pragma unroll
    for (int j = 0; j < NE; j++) s += __expf(g[j] - gm);
    scale[t] = 1.0f / s;
    int pos = atomicAdd(&counts[best], 1);
    list[best * TOK + pos] = t;
}

extern "C" void kernel_launch(void* const* d_in, const int* in_sizes, int n_in,
                              void* d_out, int out_size, void* d_ws, size_t ws_size,
                              hipStream_t stream) {
    const float* X    = (const float*)d_in[0];
    const float* G    = (const float*)d_in[1];
    const float* W    = (const float*)d_in[2];
    const float* Bias = (const float*)d_in[3];
    float* out = (float*)d_out;

    float* scale = (float*)d_ws;                               // 32 KB
    int* counts  = (int*)((char*)d_ws + 32768);                // 32 B (+pad)
    int* list    = (int*)((char*)d_ws + 36864);                // 256 KB -> ends 299008
    __bf16* Xb   = (__bf16*)((char*)d_ws + 299008);            // 16 MB
    __bf16* Wt   = (__bf16*)((char*)d_ws + 299008 + 16777216); // 16 MB
    const size_t need = 299008 + 2 * 16777216ULL;

    hipMemsetAsync(counts, 0, NE * sizeof(int), stream);

    if (ws_size >= need) {
        void* args[] = {(void*)&X, (void*)&G, (void*)&W, (void*)&Xb, (void*)&Wt,
                        (void*)&Bias, (void*)&scale, (void*)&counts, (void*)&list,
                        (void*)&out};
        hipError_t err = hipLaunchCooperativeKernel(
            (const void*)fused_moe, dim3(FGRID), dim3(256), args, 0, stream);
        if (err != hipSuccess) {
            // Cooperative launch unavailable: exact R5 two-kernel path (141.5us).
            prep_kernel<<<5120, 256, 0, stream>>>(X, G, W, Xb, Wt, scale, counts, list);
            moe_gemm_bf16<<<128 * 16 * 8, 256, 0, stream>>>(Xb, Wt, Bias, scale, counts,
                                                            list, out);
        }
    } else {
        route_fb_kernel<<<TOK / 256, 256, 0, stream>>>(G, scale, counts, list);
        moe_gemm_fb<<<NE * 64 * 8, 256, 0, stream>>>(X, W, Bias, scale, counts, list, out);
    }
}

// Round 10
// 155.986 us; speedup vs baseline: 1.5511x; 1.5511x over previous
//
#include <hip/hip_runtime.h>
#include <hip/hip_bf16.h>
#include <cstdint>
#include <cstddef>

#define TOK 8192
#define HID 1024
#define NE 8

typedef __bf16 bf16x4 __attribute__((ext_vector_type(4)));
typedef __bf16 bf16x8 __attribute__((ext_vector_type(8)));
typedef float floatx4 __attribute__((ext_vector_type(4)));

static __device__ __forceinline__ __bf16 f2bf(float x) {
    unsigned u = __builtin_bit_cast(unsigned, x);
    u += 0x7fffu + ((u >> 16) & 1u);   // RNE (inputs finite)
    unsigned short hs = (unsigned short)(u >> 16);
    return __builtin_bit_cast(__bf16, hs);
}

// Fused prep (R5-verified). Block order matters:
//   blocks [0, 1024):    W fp32 -> Wt bf16 transpose, dispatched FIRST (latency-bound,
//                        overlaps the streaming X phase instead of running as a tail).
//   blocks [1024, 5120): X fp32 -> Xb bf16; first 32 also route.
// Prep moves ~96MB -> ~15us BW roofline; R9's fusion experiment confirmed there is
// no meaningful slack here (non-GEMM budget is the harness's 2x256MB poison fills).
__global__ void prep_kernel(const float* __restrict__ X, const float* __restrict__ gate,
                            const float* __restrict__ W,
                            __bf16* __restrict__ Xb, __bf16* __restrict__ Wt,
                            float* __restrict__ scale, int* __restrict__ counts,
                            int* __restrict__ list) {
    const int b = blockIdx.x;
    const int t = threadIdx.x;

    if (b < 1024) {
        // ---- cvt_wt: 128k x 64n tile per block; thread owns 8k x 4n micro-tile. ----
        const int e  = b >> 7;
        const int rem = b & 127;
        const int kt = rem >> 4;
        const int nt = rem & 15;
        const int k0 = kt * 128, n0 = nt * 64;
        const int cg = t & 15;
        const int rg = t >> 4;

        const float* src = W + ((size_t)e * HID + k0 + rg * 8) * HID + n0 + cg * 4;
        float rr[8][4];
#pragma unroll
        for (int i = 0; i < 8; i++) {
            float4 x = *(const float4*)(src + (size_t)i * HID);
            rr[i][0] = x.x; rr[i][1] = x.y; rr[i][2] = x.z; rr[i][3] = x.w;
        }
        __bf16* dst = Wt + ((size_t)e * HID + n0 + cg * 4) * HID + k0 + rg * 8;
#pragma unroll
        for (int j = 0; j < 4; j++) {
            bf16x8 v;
#pragma unroll
            for (int i = 0; i < 8; i++) v[i] = f2bf(rr[i][j]);
            *(bf16x8*)(dst + (size_t)j * HID) = v;
        }
    } else {
        // ---- cvt_x ----
        const int bb = b - 1024;
        size_t idx = (size_t)bb * 256 + t;
        const float4 a0 = *(const float4*)(X + idx * 8);
        const float4 a1 = *(const float4*)(X + idx * 8 + 4);
        bf16x8 v;
        v[0] = f2bf(a0.x); v[1] = f2bf(a0.y); v[2] = f2bf(a0.z); v[3] = f2bf(a0.w);
        v[4] = f2bf(a1.x); v[5] = f2bf(a1.y); v[6] = f2bf(a1.z); v[7] = f2bf(a1.w);
        *(bf16x8*)(Xb + idx * 8) = v;

        // ---- route (first 32 X-blocks, one token per thread, LDS histogram) ----
        if (bb < 32) {
            __shared__ int hcnt[NE];
            __shared__ int hbase[NE];
            if (t < NE) hcnt[t] = 0;
            __syncthreads();
            int tok = bb * 256 + t;
            float g[NE];
#pragma unroll
            for (int j = 0; j < NE; j++) g[j] = gate[tok * NE + j];
            float gm = g[0]; int best = 0;
#pragma unroll
            for (int j = 1; j < NE; j++) {
                if (g[j] > gm) { gm = g[j]; best = j; }   // strict >: first-max (argmax)
            }
            float s = 0.f;
#pragma unroll
            for (int j = 0; j < NE; j++) s += __expf(g[j] - gm);
            scale[tok] = 1.0f / s;
            int lpos = atomicAdd(&hcnt[best], 1);
            __syncthreads();
            if (t < NE) hbase[t] = atomicAdd(&counts[t], hcnt[t]);
            __syncthreads();
            list[best * TOK + hbase[best] + lpos] = tok;
        }
    }
}

// Grouped GEMM, 64m x 64n tiles, DEPTH-3 PREFETCH (extends the only winning direction).
//  * Ladder evidence: depth-1 drain-0 (R2) 44us -> depth-2 counted (R3) ~38us.
//    Still MfmaUtil 15%, no busy pipe, 0 bank conflicts -> residual latency: at
//    depth-2 the oldest tile's loads have only ~400cy (2 short compute phases) in
//    flight vs L2/L3 latency 200-900cy. Depth-3 gives ~900cy.
//  * 4 LDS buffers (66KB) -> 2 blocks/CU (trade matches the R2->R3 precedent:
//    depth beat occupancy). stage(t+3) while computing t; s_waitcnt vmcnt(12)
//    (tiles t..t+3 = 16 loads outstanding, wait oldest 4). Never drain to 0.
//  * Two raw s_barriers per tile (WAR before stage; visibility before compute).
//  * T5 s_setprio(1) around MFMA cluster. Expert-per-XCD: bid&7 == e.
//  * LDS chunk swizzle c^(r&7); staging fetches global chunk (lane&7)^srow.
__launch_bounds__(256)
__global__ void moe_gemm_bf16(const __bf16* __restrict__ Xb, const __bf16* __restrict__ Wt,
                              const float* __restrict__ Bias, const float* __restrict__ scale,
                              const int* __restrict__ counts, const int* __restrict__ list,
                              float* __restrict__ out) {
    const int bid = blockIdx.x;
    const int e  = bid & 7;
    const int nt = (bid >> 3) & 15;
    const int mt = bid >> 7;

    const int cnt = counts[e];
    if (mt * 64 >= cnt) return;
    const int mvalid = min(64, cnt - mt * 64);
    const int n0 = nt * 64;

    __shared__ __bf16 As[4][64 * 64];
    __shared__ __bf16 Bs[4][64 * 64];
    __shared__ int   tok[64];
    __shared__ float scl[64];

    const int tid  = threadIdx.x;
    const int lane = tid & 63;
    const int wave = tid >> 6;

    if (tid < 64) {
        int g = mt * 64 + tid;
        int tk = (g < cnt) ? list[e * TOK + g] : 0;
        tok[tid] = tk;
        scl[tid] = (g < cnt) ? scale[tk] : 0.f;
    }
    __syncthreads();

    // Staging: A rows wave*16 + i*8 + srow (i=0..1), B rows wave*16 + i*8 + srow.
    const int srow = lane >> 3;
    const int gchunk = ((lane & 7) ^ srow) * 8;
    const __bf16* aptr[2];
    const __bf16* bptr[2];
#pragma unroll
    for (int i = 0; i < 2; i++) {
        int r = wave * 16 + i * 8 + srow;
        aptr[i] = Xb + (size_t)tok[r] * HID + gchunk;
        bptr[i] = Wt + ((size_t)e * HID + n0 + r) * HID + gchunk;
    }

    const int ln = lane & 15;
    const int q  = lane >> 4;
    const int wm = (wave >> 1) * 32;
    const int wn = (wave & 1) * 32;
    const int rsw = ln & 7;

    floatx4 acc[2][2];
#pragma unroll
    for (int mi = 0; mi < 2; mi++)
#pragma unroll
        for (int ni = 0; ni < 2; ni++) acc[mi][ni] = (floatx4){0.f, 0.f, 0.f, 0.f};

    auto stage = [&](int b, int k0) {
#pragma unroll
        for (int i = 0; i < 2; i++) {
            __builtin_amdgcn_global_load_lds(
                (const __attribute__((address_space(1))) void*)(aptr[i] + k0),
                (__attribute__((address_space(3))) void*)(&As[b][(wave * 16 + i * 8) * 64]),
                16, 0, 0);
            __builtin_amdgcn_global_load_lds(
                (const __attribute__((address_space(1))) void*)(bptr[i] + k0),
                (__attribute__((address_space(3))) void*)(&Bs[b][(wave * 16 + i * 8) * 64]),
                16, 0, 0);
        }
    };

    auto compute = [&](int b) {
        __builtin_amdgcn_s_setprio(1);
#pragma unroll
        for (int kk = 0; kk < 64; kk += 32) {
            const int cb = (kk >> 3) + q;
            const int pos = (cb ^ rsw) * 8;
            bf16x8 af[2], bfv[2];
#pragma unroll
            for (int mi = 0; mi < 2; mi++)
                af[mi] = *(const bf16x8*)(&As[b][(wm + mi * 16 + ln) * 64 + pos]);
#pragma unroll
            for (int ni = 0; ni < 2; ni++)
                bfv[ni] = *(const bf16x8*)(&Bs[b][(wn + ni * 16 + ln) * 64 + pos]);
#pragma unroll
            for (int mi = 0; mi < 2; mi++)
#pragma unroll
                for (int ni = 0; ni < 2; ni++)
                    acc[mi][ni] = __builtin_amdgcn_mfma_f32_16x16x32_bf16(
                        af[mi], bfv[ni], acc[mi][ni], 0, 0, 0);
        }
        __builtin_amdgcn_s_setprio(0);
    };

    // ---- depth-3 pipeline over 16 K-tiles, 4 LDS buffers ----
    // prologue: tiles 0,1,2 in flight (12 outstanding VMEM/wave)
    stage(0, 0);
    stage(1, 64);
    stage(2, 128);

#pragma unroll
    for (int t = 0; t < 13; ++t) {
        __builtin_amdgcn_s_barrier();                       // WAR: buf[(t+3)%4] (computed t-1) free
        stage((t + 3) % 4, (t + 3) * 64);                   // 16 outstanding (tiles t..t+3)
        asm volatile("s_waitcnt vmcnt(12)" ::: "memory");   // tile t's 4 loads (oldest) done
        __builtin_amdgcn_s_barrier();                       // tile t visible to all waves
        compute(t % 4);
    }
    // epilogue: tiles 13,14,15 outstanding (12 loads)
    asm volatile("s_waitcnt vmcnt(8)" ::: "memory");
    __builtin_amdgcn_s_barrier();
    compute(13 % 4);
    asm volatile("s_waitcnt vmcnt(4)" ::: "memory");
    __builtin_amdgcn_s_barrier();
    compute(14 % 4);
    asm volatile("s_waitcnt vmcnt(0)" ::: "memory");
    __builtin_amdgcn_s_barrier();
    compute(15 % 4);

    float bn[2];
#pragma unroll
    for (int ni = 0; ni < 2; ni++) bn[ni] = Bias[e * HID + n0 + wn + ni * 16 + ln];

#pragma unroll
    for (int mi = 0; mi < 2; mi++) {
#pragma unroll
        for (int r = 0; r < 4; r++) {
            int row = wm + mi * 16 + q * 4 + r;
            if (row < mvalid) {
                int t = tok[row];
                float sc = scl[row];
                size_t ob = (size_t)t * HID + n0 + wn + ln;
#pragma unroll
                for (int ni = 0; ni < 2; ni++)
                    __builtin_nontemporal_store(sc * (acc[mi][ni][r] + bn[ni]),
                                                &out[ob + ni * 16]);
            }
        }
    }
}

// ---------------- fallback (ws too small): direct fp32 reads, compile-time j ----------------
__launch_bounds__(256)
__global__ void moe_gemm_fb(const float* __restrict__ X, const float* __restrict__ W,
                            const float* __restrict__ Bias, const float* __restrict__ scale,
                            const int* __restrict__ counts, const int* __restrict__ list,
                            float* __restrict__ out) {
    const int bid = blockIdx.x;
    const int e  = bid >> 9;
    const int nt = (bid >> 6) & 7;
    const int mt = bid & 63;
    const int cnt = counts[e];
    if (mt * 128 >= cnt) return;
    const int mvalid = min(128, cnt - mt * 128);
    const int n0 = nt * 128;

    __shared__ __bf16 As[128 * 64];
    __shared__ __bf16 Bs[128 * 64];
    __shared__ int   tok[128];
    __shared__ float scl[128];

    const int tid = threadIdx.x;
    if (tid < 128) {
        int g = mt * 128 + tid;
        int tk = (g < cnt) ? list[e * TOK + g] : 0;
        tok[tid] = tk;
        scl[tid] = (g < cnt) ? scale[tk] : 0.f;
    }
    __syncthreads();

    const int c4 = tid & 15;
    const float* rp[8];
    bool rv[8];
#pragma unroll
    for (int i = 0; i < 8; i++) {
        int m = (tid >> 4) + 16 * i;
        rv[i] = (m < mvalid);
        rp[i] = X + (size_t)tok[m] * HID;
    }
    const int n4 = tid & 31;
    const int kb = tid >> 5;
    const float* wbase = W + (size_t)e * HID * HID + (size_t)(kb * 8) * HID + n0 + n4 * 4;

    const int lane = tid & 63;
    const int ln = lane & 15;
    const int q  = lane >> 4;
    const int wave = tid >> 6;
    const int wm = (wave >> 1) * 64;
    const int wn = (wave & 1) * 64;

    floatx4 acc[4][4];
#pragma unroll
    for (int mi = 0; mi < 4; mi++)
#pragma unroll
        for (int ni = 0; ni < 4; ni++) acc[mi][ni] = (floatx4){0.f, 0.f, 0.f, 0.f};

    for (int k0 = 0; k0 < HID; k0 += 64) {
#pragma unroll
        for (int i = 0; i < 8; i++) {
            int m = (tid >> 4) + 16 * i;
            float4 v = make_float4(0.f, 0.f, 0.f, 0.f);
            if (rv[i]) v = *(const float4*)(rp[i] + k0 + c4 * 4);
            bf16x4 b4;
            b4[0] = f2bf(v.x); b4[1] = f2bf(v.y); b4[2] = f2bf(v.z); b4[3] = f2bf(v.w);
            int chunk = c4 >> 1;
            int addr = m * 64 + ((chunk ^ (m & 7)) * 8) + (c4 & 1) * 4;
            *(bf16x4*)(&As[addr]) = b4;
        }
        {
            const float* wp = wbase + (size_t)k0 * HID;
            float4 rr[8];
#pragma unroll
            for (int r = 0; r < 8; r++) rr[r] = *(const float4*)(wp + (size_t)r * HID);
#pragma unroll
            for (int j = 0; j < 4; j++) {
                int n = n4 * 4 + j;
                int c = kb ^ (n & 7);
                bf16x8 pk;
                pk[0] = f2bf(j == 0 ? rr[0].x : j == 1 ? rr[0].y : j == 2 ? rr[0].z : rr[0].w);
                pk[1] = f2bf(j == 0 ? rr[1].x : j == 1 ? rr[1].y : j == 2 ? rr[1].z : rr[1].w);
                pk[2] = f2bf(j == 0 ? rr[2].x : j == 1 ? rr[2].y : j == 2 ? rr[2].z : rr[2].w);
                pk[3] = f2bf(j == 0 ? rr[3].x : j == 1 ? rr[3].y : j == 2 ? rr[3].z : rr[3].w);
                pk[4] = f2bf(j == 0 ? rr[4].x : j == 1 ? rr[4].y : j == 2 ? rr[4].z : rr[4].w);
                pk[5] = f2bf(j == 0 ? rr[5].x : j == 1 ? rr[5].y : j == 2 ? rr[5].z : rr[5].w);
                pk[6] = f2bf(j == 0 ? rr[6].x : j == 1 ? rr[6].y : j == 2 ? rr[6].z : rr[6].w);
                pk[7] = f2bf(j == 0 ? rr[7].x : j == 1 ? rr[7].y : j == 2 ? rr[7].z : rr[7].w);
                *(bf16x8*)(&Bs[n * 64 + c * 8]) = pk;
            }
        }
        __syncthreads();
#pragma unroll
        for (int kk = 0; kk < 64; kk += 32) {
            const int cbase = (kk >> 3) + q;
            bf16x8 af[4], bfv[4];
#pragma unroll
            for (int mi = 0; mi < 4; mi++) {
                int row = wm + mi * 16 + ln;
                af[mi] = *(const bf16x8*)(&As[row * 64 + ((cbase ^ (row & 7)) * 8)]);
            }
#pragma unroll
            for (int ni = 0; ni < 4; ni++) {
                int n = wn + ni * 16 + ln;
                bfv[ni] = *(const bf16x8*)(&Bs[n * 64 + ((cbase ^ (n & 7)) * 8)]);
            }
#pragma unroll
            for (int mi = 0; mi < 4; mi++)
#pragma unroll
                for (int ni = 0; ni < 4; ni++)
                    acc[mi][ni] = __builtin_amdgcn_mfma_f32_16x16x32_bf16(
                        af[mi], bfv[ni], acc[mi][ni], 0, 0, 0);
        }
        __syncthreads();
    }

    float bn[4];
#pragma unroll
    for (int ni = 0; ni < 4; ni++) bn[ni] = Bias[e * HID + n0 + wn + ni * 16 + ln];
#pragma unroll
    for (int mi = 0; mi < 4; mi++) {
#pragma unroll
        for (int r = 0; r < 4; r++) {
            int row = wm + mi * 16 + q * 4 + r;
            if (row < mvalid) {
                int t = tok[row];
                float sc = scl[row];
                size_t ob = (size_t)t * HID + n0 + wn + ln;
#pragma unroll
                for (int ni = 0; ni < 4; ni++)
                    out[ob + ni * 16] = sc * (acc[mi][ni][r] + bn[ni]);
            }
        }
    }
}

__global__ void route_fb_kernel(const float* __restrict__ gate, float* __restrict__ scale,
                                int* __restrict__ counts, int* __restrict__ list) {
    int t = blockIdx.x * blockDim.x + threadIdx.x;
    if (t >= TOK) return;
    float g[NE];
#pragma unroll
    for (int j = 0; j < NE; j++) g[j] = gate[t * NE + j];
    float gm = g[0]; int best = 0;
#pragma unroll
    for (int j = 1; j < NE; j++) {
        if (g[j] > gm) { gm = g[j]; best = j; }
    }
    float s = 0.f;
#pragma unroll
    for (int j = 0; j < NE; j++) s += __expf(g[j] - gm);
    scale[t] = 1.0f / s;
    int pos = atomicAdd(&counts[best], 1);
    list[best * TOK + pos] = t;
}

extern "C" void kernel_launch(void* const* d_in, const int* in_sizes, int n_in,
                              void* d_out, int out_size, void* d_ws, size_t ws_size,
                              hipStream_t stream) {
    const float* X    = (const float*)d_in[0];
    const float* G    = (const float*)d_in[1];
    const float* W    = (const float*)d_in[2];
    const float* Bias = (const float*)d_in[3];
    float* out = (float*)d_out;

    float* scale = (float*)d_ws;                               // 32 KB
    int* counts  = (int*)((char*)d_ws + 32768);                // 32 B (+pad)
    int* list    = (int*)((char*)d_ws + 36864);                // 256 KB -> ends 299008
    __bf16* Xb   = (__bf16*)((char*)d_ws + 299008);            // 16 MB
    __bf16* Wt   = (__bf16*)((char*)d_ws + 299008 + 16777216); // 16 MB
    const size_t need = 299008 + 2 * 16777216ULL;

    hipMemsetAsync(counts, 0, NE * sizeof(int), stream);

    if (ws_size >= need) {
        // 1024 W-transpose blocks FIRST (latency-bound, overlap with X streaming),
        // then 4096 X-convert blocks (first 32 of which also route).
        prep_kernel<<<5120, 256, 0, stream>>>(X, G, W, Xb, Wt, scale, counts, list);
        // grid: 128 mt x 16 nt x 8 e; inactive m-tiles exit immediately.
        moe_gemm_bf16<<<128 * 16 * 8, 256, 0, stream>>>(Xb, Wt, Bias, scale, counts, list, out);
    } else {
        route_fb_kernel<<<TOK / 256, 256, 0, stream>>>(G, scale, counts, list);
        moe_gemm_fb<<<NE * 64 * 8, 256, 0, stream>>>(X, W, Bias, scale, counts, list, out);
    }
}

// Round 12
// 142.411 us; speedup vs baseline: 1.6990x; 1.0953x over previous
//
#include <hip/hip_runtime.h>
#include <hip/hip_bf16.h>
#include <cstdint>
#include <cstddef>

#define TOK 8192
#define HID 1024
#define NE 8

typedef __bf16 bf16x4 __attribute__((ext_vector_type(4)));
typedef __bf16 bf16x8 __attribute__((ext_vector_type(8)));
typedef float floatx4 __attribute__((ext_vector_type(4)));

static __device__ __forceinline__ __bf16 f2bf(float x) {
    unsigned u = __builtin_bit_cast(unsigned, x);
    u += 0x7fffu + ((u >> 16) & 1u);   // RNE (inputs finite)
    unsigned short hs = (unsigned short)(u >> 16);
    return __builtin_bit_cast(__bf16, hs);
}

// Fused prep (R5-verified best). Block order matters:
//   blocks [0, 1024):    W fp32 -> Wt bf16 transpose, dispatched FIRST (latency-bound,
//                        overlaps the streaming X phase instead of running as a tail).
//   blocks [1024, 5120): X fp32 -> Xb bf16; first 32 also route.
// Prep moves ~96MB -> ~15us BW roofline (measured-consistent). R9's fusion probe
// confirmed no further slack here.
__global__ void prep_kernel(const float* __restrict__ X, const float* __restrict__ gate,
                            const float* __restrict__ W,
                            __bf16* __restrict__ Xb, __bf16* __restrict__ Wt,
                            float* __restrict__ scale, int* __restrict__ counts,
                            int* __restrict__ list) {
    const int b = blockIdx.x;
    const int t = threadIdx.x;

    if (b < 1024) {
        // ---- cvt_wt: 128k x 64n tile per block; thread owns 8k x 4n micro-tile. ----
        const int e  = b >> 7;
        const int rem = b & 127;
        const int kt = rem >> 4;
        const int nt = rem & 15;
        const int k0 = kt * 128, n0 = nt * 64;
        const int cg = t & 15;
        const int rg = t >> 4;

        const float* src = W + ((size_t)e * HID + k0 + rg * 8) * HID + n0 + cg * 4;
        float rr[8][4];
#pragma unroll
        for (int i = 0; i < 8; i++) {
            float4 x = *(const float4*)(src + (size_t)i * HID);
            rr[i][0] = x.x; rr[i][1] = x.y; rr[i][2] = x.z; rr[i][3] = x.w;
        }
        __bf16* dst = Wt + ((size_t)e * HID + n0 + cg * 4) * HID + k0 + rg * 8;
#pragma unroll
        for (int j = 0; j < 4; j++) {
            bf16x8 v;
#pragma unroll
            for (int i = 0; i < 8; i++) v[i] = f2bf(rr[i][j]);
            *(bf16x8*)(dst + (size_t)j * HID) = v;
        }
    } else {
        // ---- cvt_x ----
        const int bb = b - 1024;
        size_t idx = (size_t)bb * 256 + t;
        const float4 a0 = *(const float4*)(X + idx * 8);
        const float4 a1 = *(const float4*)(X + idx * 8 + 4);
        bf16x8 v;
        v[0] = f2bf(a0.x); v[1] = f2bf(a0.y); v[2] = f2bf(a0.z); v[3] = f2bf(a0.w);
        v[4] = f2bf(a1.x); v[5] = f2bf(a1.y); v[6] = f2bf(a1.z); v[7] = f2bf(a1.w);
        *(bf16x8*)(Xb + idx * 8) = v;

        // ---- route (first 32 X-blocks, one token per thread, LDS histogram) ----
        if (bb < 32) {
            __shared__ int hcnt[NE];
            __shared__ int hbase[NE];
            if (t < NE) hcnt[t] = 0;
            __syncthreads();
            int tok = bb * 256 + t;
            float g[NE];
#pragma unroll
            for (int j = 0; j < NE; j++) g[j] = gate[tok * NE + j];
            float gm = g[0]; int best = 0;
#pragma unroll
            for (int j = 1; j < NE; j++) {
                if (g[j] > gm) { gm = g[j]; best = j; }   // strict >: first-max (argmax)
            }
            float s = 0.f;
#pragma unroll
            for (int j = 0; j < NE; j++) s += __expf(g[j] - gm);
            scale[tok] = 1.0f / s;
            int lpos = atomicAdd(&hcnt[best], 1);
            __syncthreads();
            if (t < NE) hbase[t] = atomicAdd(&counts[t], hcnt[t]);
            __syncthreads();
            list[best * TOK + hbase[best] + lpos] = tok;
        }
    }
}

// Grouped GEMM, 64m x 64n tiles, DEPTH-2 PREFETCH (R3/R5-verified local optimum).
// Ladder: depth-1 drain-0 = 44us; depth-2 counted @ 3 blocks/CU = ~38us (BEST);
// depth-3 @ 2 blocks/CU = 63us (R10: lost TLP swamps extra in-flight time);
// 128-tiles, direct-to-reg, fused-persistent all worse. This is the optimum.
//  * Triple-buffered LDS (49.7KB -> 3 blocks/CU), stage(t+2) while computing t,
//    s_waitcnt vmcnt(8) -- never drain to 0 in the main loop.
//  * Two raw s_barriers per tile (WAR before stage; visibility before compute).
//  * T5 s_setprio(1) around MFMA cluster. Expert-per-XCD: bid&7 == e.
//  * LDS chunk swizzle c^(r&7); staging fetches global chunk (lane&7)^srow.
__launch_bounds__(256)
__global__ void moe_gemm_bf16(const __bf16* __restrict__ Xb, const __bf16* __restrict__ Wt,
                              const float* __restrict__ Bias, const float* __restrict__ scale,
                              const int* __restrict__ counts, const int* __restrict__ list,
                              float* __restrict__ out) {
    const int bid = blockIdx.x;
    const int e  = bid & 7;
    const int nt = (bid >> 3) & 15;
    const int mt = bid >> 7;

    const int cnt = counts[e];
    if (mt * 64 >= cnt) return;
    const int mvalid = min(64, cnt - mt * 64);
    const int n0 = nt * 64;

    __shared__ __bf16 As[3][64 * 64];
    __shared__ __bf16 Bs[3][64 * 64];
    __shared__ int   tok[64];
    __shared__ float scl[64];

    const int tid  = threadIdx.x;
    const int lane = tid & 63;
    const int wave = tid >> 6;

    if (tid < 64) {
        int g = mt * 64 + tid;
        int tk = (g < cnt) ? list[e * TOK + g] : 0;
        tok[tid] = tk;
        scl[tid] = (g < cnt) ? scale[tk] : 0.f;
    }
    __syncthreads();

    // Staging: A rows wave*16 + i*8 + srow (i=0..1), B rows wave*16 + i*8 + srow.
    const int srow = lane >> 3;
    const int gchunk = ((lane & 7) ^ srow) * 8;
    const __bf16* aptr[2];
    const __bf16* bptr[2];
#pragma unroll
    for (int i = 0; i < 2; i++) {
        int r = wave * 16 + i * 8 + srow;
        aptr[i] = Xb + (size_t)tok[r] * HID + gchunk;
        bptr[i] = Wt + ((size_t)e * HID + n0 + r) * HID + gchunk;
    }

    const int ln = lane & 15;
    const int q  = lane >> 4;
    const int wm = (wave >> 1) * 32;
    const int wn = (wave & 1) * 32;
    const int rsw = ln & 7;

    floatx4 acc[2][2];
#pragma unroll
    for (int mi = 0; mi < 2; mi++)
#pragma unroll
        for (int ni = 0; ni < 2; ni++) acc[mi][ni] = (floatx4){0.f, 0.f, 0.f, 0.f};

    auto stage = [&](int b, int k0) {
#pragma unroll
        for (int i = 0; i < 2; i++) {
            __builtin_amdgcn_global_load_lds(
                (const __attribute__((address_space(1))) void*)(aptr[i] + k0),
                (__attribute__((address_space(3))) void*)(&As[b][(wave * 16 + i * 8) * 64]),
                16, 0, 0);
            __builtin_amdgcn_global_load_lds(
                (const __attribute__((address_space(1))) void*)(bptr[i] + k0),
                (__attribute__((address_space(3))) void*)(&Bs[b][(wave * 16 + i * 8) * 64]),
                16, 0, 0);
        }
    };

    auto compute = [&](int b) {
        __builtin_amdgcn_s_setprio(1);
#pragma unroll
        for (int kk = 0; kk < 64; kk += 32) {
            const int cb = (kk >> 3) + q;
            const int pos = (cb ^ rsw) * 8;
            bf16x8 af[2], bfv[2];
#pragma unroll
            for (int mi = 0; mi < 2; mi++)
                af[mi] = *(const bf16x8*)(&As[b][(wm + mi * 16 + ln) * 64 + pos]);
#pragma unroll
            for (int ni = 0; ni < 2; ni++)
                bfv[ni] = *(const bf16x8*)(&Bs[b][(wn + ni * 16 + ln) * 64 + pos]);
#pragma unroll
            for (int mi = 0; mi < 2; mi++)
#pragma unroll
                for (int ni = 0; ni < 2; ni++)
                    acc[mi][ni] = __builtin_amdgcn_mfma_f32_16x16x32_bf16(
                        af[mi], bfv[ni], acc[mi][ni], 0, 0, 0);
        }
        __builtin_amdgcn_s_setprio(0);
    };

    // ---- depth-2 pipeline over 16 K-tiles, 3 LDS buffers ----
    stage(0, 0);
    stage(1, 64);

#pragma unroll
    for (int t = 0; t < 14; ++t) {
        __builtin_amdgcn_s_barrier();                      // WAR: buf[(t+2)%3]'s old tile done
        stage((t + 2) % 3, (t + 2) * 64);                  // 12 outstanding
        asm volatile("s_waitcnt vmcnt(8)" ::: "memory");   // tile t's 4 loads (oldest) done
        __builtin_amdgcn_s_barrier();                      // tile t visible to all waves
        compute(t % 3);
    }
    asm volatile("s_waitcnt vmcnt(4)" ::: "memory");
    __builtin_amdgcn_s_barrier();
    compute(14 % 3);
    asm volatile("s_waitcnt vmcnt(0)" ::: "memory");
    __builtin_amdgcn_s_barrier();
    compute(15 % 3);

    float bn[2];
#pragma unroll
    for (int ni = 0; ni < 2; ni++) bn[ni] = Bias[e * HID + n0 + wn + ni * 16 + ln];

#pragma unroll
    for (int mi = 0; mi < 2; mi++) {
#pragma unroll
        for (int r = 0; r < 4; r++) {
            int row = wm + mi * 16 + q * 4 + r;
            if (row < mvalid) {
                int t = tok[row];
                float sc = scl[row];
                size_t ob = (size_t)t * HID + n0 + wn + ln;
#pragma unroll
                for (int ni = 0; ni < 2; ni++)
                    __builtin_nontemporal_store(sc * (acc[mi][ni][r] + bn[ni]),
                                                &out[ob + ni * 16]);
            }
        }
    }
}

// ---------------- fallback (ws too small): direct fp32 reads, compile-time j ----------------
__launch_bounds__(256)
__global__ void moe_gemm_fb(const float* __restrict__ X, const float* __restrict__ W,
                            const float* __restrict__ Bias, const float* __restrict__ scale,
                            const int* __restrict__ counts, const int* __restrict__ list,
                            float* __restrict__ out) {
    const int bid = blockIdx.x;
    const int e  = bid >> 9;
    const int nt = (bid >> 6) & 7;
    const int mt = bid & 63;
    const int cnt = counts[e];
    if (mt * 128 >= cnt) return;
    const int mvalid = min(128, cnt - mt * 128);
    const int n0 = nt * 128;

    __shared__ __bf16 As[128 * 64];
    __shared__ __bf16 Bs[128 * 64];
    __shared__ int   tok[128];
    __shared__ float scl[128];

    const int tid = threadIdx.x;
    if (tid < 128) {
        int g = mt * 128 + tid;
        int tk = (g < cnt) ? list[e * TOK + g] : 0;
        tok[tid] = tk;
        scl[tid] = (g < cnt) ? scale[tk] : 0.f;
    }
    __syncthreads();

    const int c4 = tid & 15;
    const float* rp[8];
    bool rv[8];
#pragma unroll
    for (int i = 0; i < 8; i++) {
        int m = (tid >> 4) + 16 * i;
        rv[i] = (m < mvalid);
        rp[i] = X + (size_t)tok[m] * HID;
    }
    const int n4 = tid & 31;
    const int kb = tid >> 5;
    const float* wbase = W + (size_t)e * HID * HID + (size_t)(kb * 8) * HID + n0 + n4 * 4;

    const int lane = tid & 63;
    const int ln = lane & 15;
    const int q  = lane >> 4;
    const int wave = tid >> 6;
    const int wm = (wave >> 1) * 64;
    const int wn = (wave & 1) * 64;

    floatx4 acc[4][4];
#pragma unroll
    for (int mi = 0; mi < 4; mi++)
#pragma unroll
        for (int ni = 0; ni < 4; ni++) acc[mi][ni] = (floatx4){0.f, 0.f, 0.f, 0.f};

    for (int k0 = 0; k0 < HID; k0 += 64) {
#pragma unroll
        for (int i = 0; i < 8; i++) {
            int m = (tid >> 4) + 16 * i;
            float4 v = make_float4(0.f, 0.f, 0.f, 0.f);
            if (rv[i]) v = *(const float4*)(rp[i] + k0 + c4 * 4);
            bf16x4 b4;
            b4[0] = f2bf(v.x); b4[1] = f2bf(v.y); b4[2] = f2bf(v.z); b4[3] = f2bf(v.w);
            int chunk = c4 >> 1;
            int addr = m * 64 + ((chunk ^ (m & 7)) * 8) + (c4 & 1) * 4;
            *(bf16x4*)(&As[addr]) = b4;
        }
        {
            const float* wp = wbase + (size_t)k0 * HID;
            float4 rr[8];
#pragma unroll
            for (int r = 0; r < 8; r++) rr[r] = *(const float4*)(wp + (size_t)r * HID);
#pragma unroll
            for (int j = 0; j < 4; j++) {
                int n = n4 * 4 + j;
                int c = kb ^ (n & 7);
                bf16x8 pk;
                pk[0] = f2bf(j == 0 ? rr[0].x : j == 1 ? rr[0].y : j == 2 ? rr[0].z : rr[0].w);
                pk[1] = f2bf(j == 0 ? rr[1].x : j == 1 ? rr[1].y : j == 2 ? rr[1].z : rr[1].w);
                pk[2] = f2bf(j == 0 ? rr[2].x : j == 1 ? rr[2].y : j == 2 ? rr[2].z : rr[2].w);
                pk[3] = f2bf(j == 0 ? rr[3].x : j == 1 ? rr[3].y : j == 2 ? rr[3].z : rr[3].w);
                pk[4] = f2bf(j == 0 ? rr[4].x : j == 1 ? rr[4].y : j == 2 ? rr[4].z : rr[4].w);
                pk[5] = f2bf(j == 0 ? rr[5].x : j == 1 ? rr[5].y : j == 2 ? rr[5].z : rr[5].w);
                pk[6] = f2bf(j == 0 ? rr[6].x : j == 1 ? rr[6].y : j == 2 ? rr[6].z : rr[6].w);
                pk[7] = f2bf(j == 0 ? rr[7].x : j == 1 ? rr[7].y : j == 2 ? rr[7].z : rr[7].w);
                *(bf16x8*)(&Bs[n * 64 + c * 8]) = pk;
            }
        }
        __syncthreads();
#pragma unroll
        for (int kk = 0; kk < 64; kk += 32) {
            const int cbase = (kk >> 3) + q;
            bf16x8 af[4], bfv[4];
#pragma unroll
            for (int mi = 0; mi < 4; mi++) {
                int row = wm + mi * 16 + ln;
                af[mi] = *(const bf16x8*)(&As[row * 64 + ((cbase ^ (row & 7)) * 8)]);
            }
#pragma unroll
            for (int ni = 0; ni < 4; ni++) {
                int n = wn + ni * 16 + ln;
                bfv[ni] = *(const bf16x8*)(&Bs[n * 64 + ((cbase ^ (n & 7)) * 8)]);
            }
#pragma unroll
            for (int mi = 0; mi < 4; mi++)
#pragma unroll
                for (int ni = 0; ni < 4; ni++)
                    acc[mi][ni] = __builtin_amdgcn_mfma_f32_16x16x32_bf16(
                        af[mi], bfv[ni], acc[mi][ni], 0, 0, 0);
        }
        __syncthreads();
    }

    float bn[4];
#pragma unroll
    for (int ni = 0; ni < 4; ni++) bn[ni] = Bias[e * HID + n0 + wn + ni * 16 + ln];
#pragma unroll
    for (int mi = 0; mi < 4; mi++) {
#pragma unroll
        for (int r = 0; r < 4; r++) {
            int row = wm + mi * 16 + q * 4 + r;
            if (row < mvalid) {
                int t = tok[row];
                float sc = scl[row];
                size_t ob = (size_t)t * HID + n0 + wn + ln;
#pragma unroll
                for (int ni = 0; ni < 4; ni++)
                    out[ob + ni * 16] = sc * (acc[mi][ni][r] + bn[ni]);
            }
        }
    }
}

__global__ void route_fb_kernel(const float* __restrict__ gate, float* __restrict__ scale,
                                int* __restrict__ counts, int* __restrict__ list) {
    int t = blockIdx.x * blockDim.x + threadIdx.x;
    if (t >= TOK) return;
    float g[NE];
#pragma unroll
    for (int j = 0; j < NE; j++) g[j] = gate[t * NE + j];
    float gm = g[0]; int best = 0;
#pragma unroll
    for (int j = 1; j < NE; j++) {
        if (g[j] > gm) { gm = g[j]; best = j; }
    }
    float s = 0.f;
#pragma unroll
    for (int j = 0; j < NE; j++) s += __expf(g[j] - gm);
    scale[t] = 1.0f / s;
    int pos = atomicAdd(&counts[best], 1);
    list[best * TOK + pos] = t;
}

extern "C" void kernel_launch(void* const* d_in, const int* in_sizes, int n_in,
                              void* d_out, int out_size, void* d_ws, size_t ws_size,
                              hipStream_t stream) {
    const float* X    = (const float*)d_in[0];
    const float* G    = (const float*)d_in[1];
    const float* W    = (const float*)d_in[2];
    const float* Bias = (const float*)d_in[3];
    float* out = (float*)d_out;

    float* scale = (float*)d_ws;                               // 32 KB
    int* counts  = (int*)((char*)d_ws + 32768);                // 32 B (+pad)
    int* list    = (int*)((char*)d_ws + 36864);                // 256 KB -> ends 299008
    __bf16* Xb   = (__bf16*)((char*)d_ws + 299008);            // 16 MB
    __bf16* Wt   = (__bf16*)((char*)d_ws + 299008 + 16777216); // 16 MB
    const size_t need = 299008 + 2 * 16777216ULL;

    hipMemsetAsync(counts, 0, NE * sizeof(int), stream);

    if (ws_size >= need) {
        // 1024 W-transpose blocks FIRST (latency-bound, overlap with X streaming),
        // then 4096 X-convert blocks (first 32 of which also route).
        prep_kernel<<<5120, 256, 0, stream>>>(X, G, W, Xb, Wt, scale, counts, list);
        // grid: 128 mt x 16 nt x 8 e; inactive m-tiles exit immediately.
        moe_gemm_bf16<<<128 * 16 * 8, 256, 0, stream>>>(Xb, Wt, Bias, scale, counts, list, out);
    } else {
        route_fb_kernel<<<TOK / 256, 256, 0, stream>>>(G, scale, counts, list);
        moe_gemm_fb<<<NE * 64 * 8, 256, 0, stream>>>(X, W, Bias, scale, counts, list, out);
    }
}